// Round 18
// baseline (881.985 us; speedup 1.0000x reference)
//
#include <hip/hip_runtime.h>

#define HH 384
#define WW 1280

typedef unsigned short u16;
typedef unsigned int u32;
typedef __attribute__((ext_vector_type(8))) short short8;
typedef __attribute__((ext_vector_type(8))) unsigned short u16x8;
typedef __attribute__((ext_vector_type(4))) float f32x4;

__device__ __forceinline__ float bf2f(u16 u){ union{u32 i;float f;}v; v.i=((u32)u)<<16; return v.f; }
__device__ __forceinline__ u16 f2bf(float f){ union{float f;u32 i;}v; v.f=f; u32 r=v.i+0x7fffu+((v.i>>16)&1u); return (u16)(r>>16); }
__device__ __forceinline__ float ftanh(float x){
  float e = __expf(2.0f*x);
  return 1.0f - 2.0f/(e+1.0f);
}
__device__ __forceinline__ void gload_lds16(const void* g, void* l){
  __builtin_amdgcn_global_load_lds((const __attribute__((address_space(1))) void*)g,
                                   (__attribute__((address_space(3))) void*)l, 16, 0, 0);
}

// Repack W1..W3 (OIHW f32) -> wf[layer][tap][oc][ic'] bf16 (conv64 swizzle
// pre-inverted: ic' = ic ^ ((oc&7)<<3)), and W0 -> wq0[oc][k] bf16 with
// k = ic*9 + dy*3 + dx (k<27; 27..31 zero) for the conv0 im2col MFMA.
__global__ __launch_bounds__(256) void prep_weights(const float* __restrict__ W1,
    const float* __restrict__ W2, const float* __restrict__ W3,
    const float* __restrict__ W0, u16* __restrict__ wf, u16* __restrict__ wq0){
  int idx = blockIdx.x*256 + threadIdx.x;          // 110592 + 2048
  if (idx < 110592){
    int m    = idx & 63;
    int oc   = (idx>>6) & 63;
    int tap  = (idx>>12) % 9;
    int layer= idx / 36864;
    int ic   = m ^ ((oc&7)<<3);
    const float* Ws = layer==0 ? W1 : (layer==1 ? W2 : W3);
    wf[idx] = f2bf(Ws[(oc*64+ic)*9 + tap]);
  } else if (idx < 110592 + 2048){
    int j  = idx - 110592;       // j = oc*32 + k
    int k  = j & 31;
    int oc = j >> 5;
    u16 v = 0;
    if (k < 27){
      int ic = k/9, rem = k - ic*9, dy = rem/3, dx = rem - dy*3;
      v = f2bf(W0[(oc*3+ic)*9 + dy*3 + dx]);
    }
    wq0[j] = v;
  }
}

// Fused layer0+layer1. Per block (64x * 4y out tile, image n):
//  Phase 1: stage f32 img halo FB[3][8][68] (rows y0-2.., cols x0-2..),
//           overlaid on wbuf[2] (not weight-staged until tap 0).
//  Phase 2: conv0 im2col MFMA (K=27->32) over 6x66 halo tile, swapped
//           orientation (lane = px col, 4 consecutive oc/lane) -> swizzled
//           ushort4 ds_writes into tile[6][66][64] (conv64 layout).
//           OOB rows/cols written as ZERO (conv1 pads conv0's OUTPUT).
//  Phase 3: layer1 = conv64 tap loop (unchanged), tanh epilogue -> out.
__global__ __launch_bounds__(256) void conv01_kernel(const float* __restrict__ l,
    const float* __restrict__ r, const u16* __restrict__ wq0,
    const float* __restrict__ b0, const u16* __restrict__ wfL,
    const float* __restrict__ bias, u16* __restrict__ out){
  __shared__ __align__(16) u16 tile[6*66*64];      // 50688 B
  __shared__ __align__(16) u16 wbuf[3][4096];      // 3 x 8192 B
  float* FB = (float*)&wbuf[2][0];                 // 6528 B overlay (phase 1-2 only)
  const int tid = threadIdx.x;
  int id = blockIdx.x;
  id = (id & 7)*960 + (id >> 3);     // bijective: 7680 = 8*960
  const int x0 = (id % 20)*64;
  const int y0 = ((id / 20) % 96)*4;
  const int n  = id / 1920;
  const float* img = (n < 2 ? l : r) + (size_t)(n & 1)*3*HH*WW;

  const int lane = tid & 63;
  const int wv  = tid >> 6;
  const int l15 = lane & 15;
  const int lh  = lane >> 4;

  // W0 A-operand fragments (oc = mo*16+l15, k = lh*8..+7) + bias
  short8 wf0[4];
  #pragma unroll
  for (int mo=0; mo<4; ++mo)
    wf0[mo] = *(const short8*)(wq0 + (size_t)(mo*16 + l15)*32 + lh*8);
  float4 bv0[4];
  #pragma unroll
  for (int mo=0; mo<4; ++mo) bv0[mo] = *(const float4*)&b0[mo*16 + lh*4];

  // Phase 1: stage img halo (1632 f32)
  #pragma unroll
  for (int it=0; it<7; ++it){
    int e = it*256 + tid;
    if (e < 1632){
      int ch  = e / 544;
      int rem = e - ch*544;
      int row = rem / 68;
      int col = rem - row*68;
      int gy = y0 - 2 + row, gx = x0 - 2 + col;
      float v = 0.f;
      if ((unsigned)gy < (unsigned)HH && (unsigned)gx < (unsigned)WW)
        v = img[((size_t)ch*HH + gy)*WW + gx];
      FB[e] = v;
    }
  }
#define PREFW(t) do{ \
    _Pragma("unroll") \
    for (int c=0;c<2;++c){ \
      int q = c*256 + tid; \
      gload_lds16(wfL + (size_t)(t)*4096 + (size_t)q*8, &wbuf[(t)%3][(q & ~63)*8]); \
    } }while(0)
  PREFW(0); PREFW(1);
  __syncthreads();                   // FB visible; all vmcnt drained

  // per-lane k decode (k = lh*8+e)
  int icE[8], dyE[8], dxE[8]; bool okE[8];
  #pragma unroll
  for (int e=0;e<8;++e){
    int k = lh*8+e;
    okE[e] = (k < 27);
    int kk = okE[e] ? k : 0;
    icE[e] = kk/9; int rem = kk - icE[e]*9; dyE[e] = rem/3; dxE[e] = rem - dyE[e]*3;
  }

  // Phase 2: 30 units (ry in [0,6), cf in [0,5)), unit U = i*4 + wv
  #pragma unroll
  for (int i=0; i<8; ++i){
    int U = i*4 + wv;
    if (U < 30){
      int ry = U/5, cf = U - ry*5;
      int p  = cf*16 + l15 - 1;      // px rel to x0; tcol = p+1
      float v[8];
      #pragma unroll
      for (int e=0;e<8;++e){
        int fcol = cf*16 + l15 + dxE[e]; if (fcol > 67) fcol = 67;
        int frow = ry + dyE[e];
        float t = FB[icE[e]*544 + frow*68 + fcol];
        v[e] = okE[e] ? t : 0.f;
      }
      short8 xf;
      #pragma unroll
      for (int e=0;e<8;++e) xf[e] = (short)f2bf(v[e]);
      f32x4 acc0[4];
      #pragma unroll
      for (int mo=0;mo<4;++mo){
        acc0[mo] = (f32x4){0.f,0.f,0.f,0.f};
        acc0[mo] = __builtin_amdgcn_mfma_f32_16x16x32_bf16(wf0[mo], xf, acc0[mo], 0,0,0);
      }
      if (p <= 64){
        int tcol = p + 1;
        int orow = y0 - 1 + ry;
        int gxo  = x0 + p;
        bool okpx = ((unsigned)orow < (unsigned)HH) && ((unsigned)gxo < (unsigned)WW);
        char* tb = (char*)tile;
        #pragma unroll
        for (int mo=0;mo<4;++mo){
          float t0 = okpx ? ftanh(acc0[mo][0] + bv0[mo].x) : 0.f;
          float t1 = okpx ? ftanh(acc0[mo][1] + bv0[mo].y) : 0.f;
          float t2 = okpx ? ftanh(acc0[mo][2] + bv0[mo].z) : 0.f;
          float t3 = okpx ? ftanh(acc0[mo][3] + bv0[mo].w) : 0.f;
          ushort4 pv;
          pv.x = f2bf(t0); pv.y = f2bf(t1); pv.z = f2bf(t2); pv.w = f2bf(t3);
          *(ushort4*)(tb + (ry*66 + tcol)*128 + ((mo*32 + lh*8) ^ ((tcol&7)<<4))) = pv;
        }
      }
    }
  }
  __syncthreads();                   // tile visible; vmcnt drained

  // Phase 3: layer1 tap loop (identical to conv64), tanh epilogue
  f32x4 acc[4][4];
  #pragma unroll
  for (int mt=0;mt<4;++mt)
    #pragma unroll
    for (int nt=0;nt<4;++nt) acc[mt][nt] = (f32x4){0.f,0.f,0.f,0.f};

  #pragma unroll
  for (int tap = 0; tap < 9; ++tap){
    const int dy = tap/3, dx = tap%3;
    if (tap <= 6){ PREFW(tap+2); }
    const char* wb = (const char*)wbuf[tap%3];
    const char* tb = (const char*)tile;
    const int xorA = ((l15 + dx)&7)<<4;
    const int xorB = (l15&7)<<4;
    #pragma unroll
    for (int kh=0; kh<2; ++kh){
      const int kbyte = kh*64 + lh*16;
      short8 a[4], b[4];
      #pragma unroll
      for (int mt=0; mt<4; ++mt){
        int col = mt*16 + l15 + dx;
        a[mt] = *(const short8*)(tb + ((wv+dy)*66 + col)*128 + (kbyte ^ xorA));
      }
      #pragma unroll
      for (int nt=0; nt<4; ++nt){
        int oc = nt*16 + l15;
        b[nt] = *(const short8*)(wb + oc*128 + (kbyte ^ xorB));
      }
      #pragma unroll
      for (int mt=0; mt<4; ++mt)
        #pragma unroll
        for (int nt=0; nt<4; ++nt)
          acc[mt][nt] = __builtin_amdgcn_mfma_f32_16x16x32_bf16(a[mt], b[nt], acc[mt][nt], 0,0,0);
    }
    if (tap < 8){
      if (tap <= 6) asm volatile("s_waitcnt vmcnt(2)" ::: "memory");
      else          asm volatile("s_waitcnt vmcnt(0)" ::: "memory");
      __builtin_amdgcn_s_barrier();
      __builtin_amdgcn_sched_barrier(0);
    }
  }
#undef PREFW

  float bv[4];
  #pragma unroll
  for (int nt=0;nt<4;++nt) bv[nt] = bias[nt*16 + l15];
  const int gy = y0 + wv;
  u16* outR = out + (size_t)n*HH*WW*64 + (size_t)gy*WW*64;
  #pragma unroll
  for (int mt=0; mt<4; ++mt){
    #pragma unroll
    for (int rr=0; rr<4; ++rr){
      int x = x0 + mt*16 + lh*4 + rr;
      u16* op = outR + (size_t)x*64 + l15;
      #pragma unroll
      for (int nt=0; nt<4; ++nt){
        float v = acc[mt][nt][rr] + bv[nt];
        v = ftanh(v);
        op[nt*16] = f2bf(v);
      }
    }
  }
}

// Layers 2-3: 64->64 conv as 9 shifted MFMA GEMMs. NHWC bf16 in/out.
// Merged L/R: 7680 blocks, 1-D grid with XCD-bijective swizzle (7680 = 8*960).
template<bool TANH>
__global__ __launch_bounds__(256) void conv64_kernel(const u16* __restrict__ in,
    const u16* __restrict__ wfL, const float* __restrict__ bias,
    const u16* __restrict__ zpad, u16* __restrict__ out){
  __shared__ __align__(16) u16 tile[6*66*64];      // 50688 B
  __shared__ __align__(16) u16 wbuf[3][4096];      // 3 x 8192 B
  const int tid = threadIdx.x;
  int id = blockIdx.x;
  id = (id & 7)*960 + (id >> 3);     // bijective: 7680 = 8*960
  const int x0 = (id % 20)*64;
  const int y0 = ((id / 20) % 96)*4;
  const int n  = id / 1920;          // [0,4): image index
  const u16* inN = in + (size_t)n*HH*WW*64;

  // stage input tile: 3168 16B-chunks, chunk q = (row*66+col)*8 + j
  for (int q0 = 0; q0 < 3168; q0 += 256){
    int q = q0 + tid;
    if (q < 3168){
      int row = q / 528;
      int rem = q - row*528;
      int col = rem >> 3;
      int j   = rem & 7;
      int gy = y0 - 1 + row;
      int gx = x0 - 1 + col;
      const u16* g;
      if ((unsigned)gy < (unsigned)HH && (unsigned)gx < (unsigned)WW)
        g = inN + (((size_t)(gy*WW + gx))<<6) + ((j ^ (col&7))<<3);
      else
        g = zpad + (j<<3);
      gload_lds16(g, &tile[(size_t)(q & ~63)*8]);
    }
  }
  // stage weights taps 0,1 -> wbuf[0], wbuf[1]
  #pragma unroll
  for (int t=0; t<2; ++t)
    #pragma unroll
    for (int c=0; c<2; ++c){
      int q = c*256 + tid;
      gload_lds16(wfL + (size_t)t*4096 + (size_t)q*8, &wbuf[t][(q & ~63)*8]);
    }
  asm volatile("s_waitcnt vmcnt(2)" ::: "memory");
  __builtin_amdgcn_s_barrier();
  __builtin_amdgcn_sched_barrier(0);

  const int lane = tid & 63;
  const int wv = tid >> 6;
  const int l15 = lane & 15;
  const int lh  = lane >> 4;

  f32x4 acc[4][4];
  #pragma unroll
  for (int mt=0;mt<4;++mt)
    #pragma unroll
    for (int nt=0;nt<4;++nt) acc[mt][nt] = (f32x4){0.f,0.f,0.f,0.f};

  #pragma unroll
  for (int tap = 0; tap < 9; ++tap){
    const int dy = tap/3, dx = tap%3;
    if (tap <= 6){               // prefetch tap+2 weights (2-deep pipeline)
      const u16* wsrc = wfL + (size_t)(tap+2)*4096;
      u16* wdst = wbuf[(tap+2)%3];
      #pragma unroll
      for (int c=0;c<2;++c){
        int q = c*256 + tid;
        gload_lds16(wsrc + (size_t)q*8, &wdst[(q & ~63)*8]);
      }
    }
    const char* wb = (const char*)wbuf[tap%3];
    const char* tb = (const char*)tile;
    const int xorA = ((l15 + dx)&7)<<4;
    const int xorB = (l15&7)<<4;
    #pragma unroll
    for (int kh=0; kh<2; ++kh){
      const int kbyte = kh*64 + lh*16;
      short8 a[4], b[4];
      #pragma unroll
      for (int mt=0; mt<4; ++mt){
        int col = mt*16 + l15 + dx;
        a[mt] = *(const short8*)(tb + ((wv+dy)*66 + col)*128 + (kbyte ^ xorA));
      }
      #pragma unroll
      for (int nt=0; nt<4; ++nt){
        int oc = nt*16 + l15;
        b[nt] = *(const short8*)(wb + oc*128 + (kbyte ^ xorB));
      }
      #pragma unroll
      for (int mt=0; mt<4; ++mt)
        #pragma unroll
        for (int nt=0; nt<4; ++nt)
          acc[mt][nt] = __builtin_amdgcn_mfma_f32_16x16x32_bf16(a[mt], b[nt], acc[mt][nt], 0,0,0);
    }
    if (tap < 8){
      if (tap <= 6) asm volatile("s_waitcnt vmcnt(2)" ::: "memory");
      else          asm volatile("s_waitcnt vmcnt(0)" ::: "memory");
      __builtin_amdgcn_s_barrier();
      __builtin_amdgcn_sched_barrier(0);
    }
  }

  float bv[4];
  #pragma unroll
  for (int nt=0;nt<4;++nt) bv[nt] = bias[nt*16 + l15];
  const int gy = y0 + wv;
  u16* outR = out + (size_t)n*HH*WW*64 + (size_t)gy*WW*64;
  #pragma unroll
  for (int mt=0; mt<4; ++mt){
    #pragma unroll
    for (int r=0; r<4; ++r){
      int x = x0 + mt*16 + lh*4 + r;
      u16* op = outR + (size_t)x*64 + l15;
      #pragma unroll
      for (int nt=0; nt<4; ++nt){
        float v = acc[mt][nt][r] + bv[nt];
        if (TANH) v = ftanh(v);
        op[nt*16] = f2bf(v);
      }
    }
  }
}

// Correlation via banded MFMA GEMM, operands straight from global.
// phi layout: [4 images][H][W][64]; images 0,1 = left, 2,3 = right.
__global__ __launch_bounds__(256) void corr_kernel(const u16* __restrict__ phi,
    float* __restrict__ out){
  __shared__ __align__(16) float band[128*65];     // 33280 B
  const int tid = threadIdx.x;
  int id = blockIdx.x;
  id = (id & 7)*1920 + (id >> 3);    // bijective: 15360 = 8*1920
  const int x0 = (id % 20)*64;
  const int y  = (id / 20) % 384;
  const int b  = id / 7680;
  const u16* Lrow = phi + ((size_t)((b    )*HH + y)*WW)*64;
  const u16* Rrow = phi + ((size_t)((b + 2)*HH + y)*WW)*64;

  const int lane = tid & 63;
  const int wv   = tid >> 6;        // wave owns G cols [wv*48, wv*48+48)
  const int l15  = lane & 15;
  const int lh   = lane >> 4;

  f32x4 acc[4][3];
  #pragma unroll
  for (int mt=0;mt<4;++mt)
    #pragma unroll
    for (int nt=0;nt<3;++nt) acc[mt][nt] = (f32x4){0.f,0.f,0.f,0.f};

  #pragma unroll
  for (int kh=0; kh<2; ++kh){
    const int koff = kh*32 + lh*8;  // u16 units within a pixel's 64 channels
    short8 a[4], bb[3];
    #pragma unroll
    for (int mt=0; mt<4; ++mt)
      a[mt] = *(const short8*)(Lrow + (size_t)(x0 + mt*16 + l15)*64 + koff);
    #pragma unroll
    for (int nt=0; nt<3; ++nt){
      int gx = x0 - 128 + wv*48 + nt*16 + l15;
      short8 z = (short8){0,0,0,0,0,0,0,0};
      bb[nt] = (gx >= 0) ? *(const short8*)(Rrow + (size_t)gx*64 + koff) : z;
    }
    #pragma unroll
    for (int mt=0; mt<4; ++mt)
      #pragma unroll
      for (int nt=0; nt<3; ++nt)
        acc[mt][nt] = __builtin_amdgcn_mfma_f32_16x16x32_bf16(a[mt], bb[nt], acc[mt][nt], 0,0,0);
  }

  // scatter diagonal band: x = D-row, jr = D-col, d = x - jr + 128
  #pragma unroll
  for (int mt=0; mt<4; ++mt){
    #pragma unroll
    for (int nt=0; nt<3; ++nt){
      int jr = wv*48 + nt*16 + l15;
      #pragma unroll
      for (int r=0; r<4; ++r){
        int x = mt*16 + lh*4 + r;
        int d = x - jr + 128;
        if ((unsigned)d < 128u) band[d*65 + x] = acc[mt][nt][r];
      }
    }
  }
  __syncthreads();

  // write out: 2048 float4 chunks (128 d-rows x 16), 256B contiguous per d-row
  float* ob = out + ((size_t)(b*128)*HH + (size_t)y)*WW + x0;
  #pragma unroll
  for (int it=0; it<8; ++it){
    int c = it*256 + tid;
    int d = c>>4, xq = c&15;
    const float* bp = &band[d*65 + xq*4];
    float4 v = make_float4(bp[0], bp[1], bp[2], bp[3]);
    *(float4*)&ob[(size_t)d*HH*WW + xq*4] = v;
  }
}

extern "C" void kernel_launch(void* const* d_in, const int* in_sizes, int n_in,
                              void* d_out, int out_size, void* d_ws, size_t ws_size,
                              hipStream_t stream){
  const float* l  = (const float*)d_in[0];
  const float* r  = (const float*)d_in[1];
  const float* W0 = (const float*)d_in[2];
  const float* b0 = (const float*)d_in[3];
  const float* W1 = (const float*)d_in[4];
  const float* b1 = (const float*)d_in[5];
  const float* W2 = (const float*)d_in[6];
  const float* b2 = (const float*)d_in[7];
  const float* W3 = (const float*)d_in[8];
  const float* b3 = (const float*)d_in[9];
  float* out = (float*)d_out;

  u16* wf   = (u16*)d_ws;                            // 110592 u16
  u16* wq0  = (u16*)((char*)d_ws + (512u<<10));      // 2048 u16 (conv0 B)
  u16* zpad = (u16*)((char*)d_ws + (1u<<20));        // 256 B zeros
  u16* B    = (u16*)((char*)d_ws + (2u<<20));        // ws feature buf [4][H][W][64]
  u16* A    = (u16*)d_out;                           // ping scratch inside d_out

  hipMemsetAsync(zpad, 0, 256, stream);
  prep_weights<<<dim3(440), dim3(256), 0, stream>>>(W1, W2, W3, W0, wf, wq0);

  conv01_kernel<<<dim3(7680), dim3(256), 0, stream>>>(l, r, wq0, b0, wf + 0*36864, b1, B);
  conv64_kernel<true ><<<dim3(7680), dim3(256), 0, stream>>>(B, wf + 1*36864, b2, zpad, A);
  conv64_kernel<false><<<dim3(7680), dim3(256), 0, stream>>>(A, wf + 2*36864, b3, zpad, B);

  corr_kernel<<<dim3(15360), dim3(256), 0, stream>>>(B, out);
}

// Round 19
// 849.847 us; speedup vs baseline: 1.0378x; 1.0378x over previous
//
#include <hip/hip_runtime.h>

#define HH 384
#define WW 1280

typedef unsigned short u16;
typedef unsigned int u32;
typedef __attribute__((ext_vector_type(8))) short short8;
typedef __attribute__((ext_vector_type(8))) unsigned short u16x8;
typedef __attribute__((ext_vector_type(4))) float f32x4;

__device__ __forceinline__ float bf2f(u16 u){ union{u32 i;float f;}v; v.i=((u32)u)<<16; return v.f; }
__device__ __forceinline__ u16 f2bf(float f){ union{float f;u32 i;}v; v.f=f; u32 r=v.i+0x7fffu+((v.i>>16)&1u); return (u16)(r>>16); }
__device__ __forceinline__ float ftanh(float x){
  float e = __expf(2.0f*x);
  return 1.0f - 2.0f/(e+1.0f);
}
__device__ __forceinline__ void gload_lds16(const void* g, void* l){
  __builtin_amdgcn_global_load_lds((const __attribute__((address_space(1))) void*)g,
                                   (__attribute__((address_space(3))) void*)l, 16, 0, 0);
}

// Repack W1..W3 (OIHW f32) -> wf[layer][tap][oc][ic'] bf16 (conv64 swizzle
// pre-inverted: ic' = ic ^ ((oc&7)<<3)), and W0 -> wq0[oc][k] bf16 with
// k = ic*9 + dy*3 + dx (k<27; 27..31 zero) for the conv0 im2col MFMA.
__global__ __launch_bounds__(256) void prep_weights(const float* __restrict__ W1,
    const float* __restrict__ W2, const float* __restrict__ W3,
    const float* __restrict__ W0, u16* __restrict__ wf, u16* __restrict__ wq0){
  int idx = blockIdx.x*256 + threadIdx.x;          // 110592 + 2048
  if (idx < 110592){
    int m    = idx & 63;
    int oc   = (idx>>6) & 63;
    int tap  = (idx>>12) % 9;
    int layer= idx / 36864;
    int ic   = m ^ ((oc&7)<<3);
    const float* Ws = layer==0 ? W1 : (layer==1 ? W2 : W3);
    wf[idx] = f2bf(Ws[(oc*64+ic)*9 + tap]);
  } else if (idx < 110592 + 2048){
    int j  = idx - 110592;       // j = oc*32 + k
    int k  = j & 31;
    int oc = j >> 5;
    u16 v = 0;
    if (k < 27){
      int ic = k/9, rem = k - ic*9, dy = rem/3, dx = rem - dy*3;
      v = f2bf(W0[(oc*3+ic)*9 + dy*3 + dx]);
    }
    wq0[j] = v;
  }
}

// Layer 0 via im2col MFMA, LDS-staged gather. Block: 64x * 4y, 64 oc.
// Phase 1: stage f32 halo FB[3 ic][6 rows][72 cols] (col c <-> gx = x0-4+c,
// rows y0-1..y0+4) with aligned float4 loads; OOB -> 0. 80-float zero slot
// at FB[1296..] serves the k>=27 K-padding lanes.
// Phase 2: one 16x16x32 MFMA per (16px x 16oc) tile (K=27->32); lane
// (l15,lh) = pixel x0+mt*16+l15, k-chunk lh*8..+7, gathered via ds_read_b32
// from per-lane precomputed bases (no bounds checks in the loop).
__global__ __launch_bounds__(256) void conv0_kernel(const float* __restrict__ l,
    const float* __restrict__ r, const u16* __restrict__ wq0,
    const float* __restrict__ b0, u16* __restrict__ out){
  __shared__ __align__(16) float FB[1376];
  const int tid = threadIdx.x;
  const int x0 = blockIdx.x*64;
  const int y0 = blockIdx.y*4;
  const int n  = blockIdx.z;
  const float* img = (n < 2 ? l : r) + (size_t)(n & 1)*3*HH*WW;

  // Phase 1: 344 float4 chunks (324 halo + 20 zero-slot)
  #pragma unroll
  for (int it=0; it<2; ++it){
    int e = it*256 + tid;
    if (e < 344){
      float4 v = make_float4(0.f,0.f,0.f,0.f);
      if (e < 324){
        int ic  = e / 108;
        int rem = e - ic*108;
        int row = rem / 18;
        int c4  = rem - row*18;
        int gy  = y0 - 1 + row;
        int gx0 = x0 - 4 + c4*4;
        if ((unsigned)gy < (unsigned)HH){
          const float* rp = img + ((size_t)ic*HH + gy)*WW;
          if (gx0 >= 0 && gx0 + 3 < WW){
            v = *(const float4*)(rp + gx0);
          } else {
            if ((unsigned)(gx0+0) < (unsigned)WW) v.x = rp[gx0+0];
            if ((unsigned)(gx0+1) < (unsigned)WW) v.y = rp[gx0+1];
            if ((unsigned)(gx0+2) < (unsigned)WW) v.z = rp[gx0+2];
            if ((unsigned)(gx0+3) < (unsigned)WW) v.w = rp[gx0+3];
          }
        }
      }
      *(float4*)&FB[e*4] = v;
    }
  }
  __syncthreads();

  const int lane = tid & 63;
  const int wv  = tid >> 6;
  const int l15 = lane & 15;
  const int lh  = lane >> 4;
  const int y   = y0 + wv;

  // per-lane k decode + LDS base (k = lh*8+e); k>=27 -> zero slot
  int baseE[8];
  #pragma unroll
  for (int e=0; e<8; ++e){
    int k  = lh*8 + e;
    bool ok = (k < 27);
    int kk = ok ? k : 0;
    int ic = kk/9, rem = kk - ic*9, dy = rem/3, dx = rem - dy*3;
    baseE[e] = ok ? (ic*432 + (wv + dy)*72 + dx + 3) : 1296;
  }

  // B-fragments: oc = nt*16 + l15, k-chunk lh*8 (prepacked bf16)
  short8 b[4];
  #pragma unroll
  for (int nt=0; nt<4; ++nt)
    b[nt] = *(const short8*)(wq0 + (size_t)(nt*16 + l15)*32 + lh*8);

  // A-fragments: LDS gather + bf16 pack
  short8 a[4];
  #pragma unroll
  for (int mt=0; mt<4; ++mt){
    int off = mt*16 + l15;
    float v[8];
    #pragma unroll
    for (int e=0; e<8; ++e) v[e] = FB[baseE[e] + off];
    short8 af;
    #pragma unroll
    for (int e=0; e<8; ++e) af[e] = (short)f2bf(v[e]);
    a[mt] = af;
  }

  f32x4 acc[4][4];
  #pragma unroll
  for (int mt=0;mt<4;++mt)
    #pragma unroll
    for (int nt=0;nt<4;++nt) acc[mt][nt] = (f32x4){0.f,0.f,0.f,0.f};
  #pragma unroll
  for (int mt=0; mt<4; ++mt)
    #pragma unroll
    for (int nt=0; nt<4; ++nt)
      acc[mt][nt] = __builtin_amdgcn_mfma_f32_16x16x32_bf16(a[mt], b[nt], acc[mt][nt], 0,0,0);

  float bv[4];
  #pragma unroll
  for (int nt=0;nt<4;++nt) bv[nt] = b0[nt*16 + l15];
  u16* outR = out + (size_t)n*HH*WW*64 + (size_t)y*WW*64;
  #pragma unroll
  for (int mt=0; mt<4; ++mt){
    #pragma unroll
    for (int rr=0; rr<4; ++rr){
      int x = x0 + mt*16 + lh*4 + rr;
      u16* op = outR + (size_t)x*64 + l15;
      #pragma unroll
      for (int nt=0; nt<4; ++nt){
        float v = acc[mt][nt][rr] + bv[nt];
        v = ftanh(v);
        op[nt*16] = f2bf(v);
      }
    }
  }
}

// Layers 1-3: 64->64 conv as 9 shifted MFMA GEMMs. NHWC bf16 in/out.
// Merged L/R: 7680 blocks, 1-D grid with XCD-bijective swizzle (7680 = 8*960).
// Block: 256 px (64x * 4y) x 64 oc; wave w owns y-row y0+w, M=64 N=64 (4x4 frags).
// Input LDS [6 rows][66 cols][64 ic] swizzled, staged linearly from
// pre-swizzled src. Weight LDS wbuf[3], staged 2 taps ahead, counted-vmcnt
// raw barriers (no vmcnt(0) drain in the tap loop).
template<bool TANH>
__global__ __launch_bounds__(256) void conv64_kernel(const u16* __restrict__ in,
    const u16* __restrict__ wfL, const float* __restrict__ bias,
    const u16* __restrict__ zpad, u16* __restrict__ out){
  __shared__ __align__(16) u16 tile[6*66*64];      // 50688 B
  __shared__ __align__(16) u16 wbuf[3][4096];      // 3 x 8192 B
  const int tid = threadIdx.x;
  int id = blockIdx.x;
  id = (id & 7)*960 + (id >> 3);     // bijective: 7680 = 8*960
  const int x0 = (id % 20)*64;
  const int y0 = ((id / 20) % 96)*4;
  const int n  = id / 1920;          // [0,4): image index
  const u16* inN = in + (size_t)n*HH*WW*64;

  // stage input tile: 3168 16B-chunks, chunk q = (row*66+col)*8 + j
  for (int q0 = 0; q0 < 3168; q0 += 256){
    int q = q0 + tid;
    if (q < 3168){
      int row = q / 528;
      int rem = q - row*528;
      int col = rem >> 3;
      int j   = rem & 7;
      int gy = y0 - 1 + row;
      int gx = x0 - 1 + col;
      const u16* g;
      if ((unsigned)gy < (unsigned)HH && (unsigned)gx < (unsigned)WW)
        g = inN + (((size_t)(gy*WW + gx))<<6) + ((j ^ (col&7))<<3);
      else
        g = zpad + (j<<3);
      gload_lds16(g, &tile[(size_t)(q & ~63)*8]);
    }
  }
  // stage weights taps 0,1 -> wbuf[0], wbuf[1]
  #pragma unroll
  for (int t=0; t<2; ++t)
    #pragma unroll
    for (int c=0; c<2; ++c){
      int q = c*256 + tid;
      gload_lds16(wfL + (size_t)t*4096 + (size_t)q*8, &wbuf[t][(q & ~63)*8]);
    }
  asm volatile("s_waitcnt vmcnt(2)" ::: "memory");
  __builtin_amdgcn_s_barrier();
  __builtin_amdgcn_sched_barrier(0);

  const int lane = tid & 63;
  const int wv = tid >> 6;
  const int l15 = lane & 15;
  const int lh  = lane >> 4;

  f32x4 acc[4][4];
  #pragma unroll
  for (int mt=0;mt<4;++mt)
    #pragma unroll
    for (int nt=0;nt<4;++nt) acc[mt][nt] = (f32x4){0.f,0.f,0.f,0.f};

  #pragma unroll
  for (int tap = 0; tap < 9; ++tap){
    const int dy = tap/3, dx = tap%3;
    if (tap <= 6){               // prefetch tap+2 weights (2-deep pipeline)
      const u16* wsrc = wfL + (size_t)(tap+2)*4096;
      u16* wdst = wbuf[(tap+2)%3];
      #pragma unroll
      for (int c=0;c<2;++c){
        int q = c*256 + tid;
        gload_lds16(wsrc + (size_t)q*8, &wdst[(q & ~63)*8]);
      }
    }
    const char* wb = (const char*)wbuf[tap%3];
    const char* tb = (const char*)tile;
    const int xorA = ((l15 + dx)&7)<<4;
    const int xorB = (l15&7)<<4;
    #pragma unroll
    for (int kh=0; kh<2; ++kh){
      const int kbyte = kh*64 + lh*16;
      short8 a[4], b[4];
      #pragma unroll
      for (int mt=0; mt<4; ++mt){
        int col = mt*16 + l15 + dx;
        a[mt] = *(const short8*)(tb + ((wv+dy)*66 + col)*128 + (kbyte ^ xorA));
      }
      #pragma unroll
      for (int nt=0; nt<4; ++nt){
        int oc = nt*16 + l15;
        b[nt] = *(const short8*)(wb + oc*128 + (kbyte ^ xorB));
      }
      #pragma unroll
      for (int mt=0; mt<4; ++mt)
        #pragma unroll
        for (int nt=0; nt<4; ++nt)
          acc[mt][nt] = __builtin_amdgcn_mfma_f32_16x16x32_bf16(a[mt], b[nt], acc[mt][nt], 0,0,0);
    }
    if (tap < 8){
      if (tap <= 6) asm volatile("s_waitcnt vmcnt(2)" ::: "memory");
      else          asm volatile("s_waitcnt vmcnt(0)" ::: "memory");
      __builtin_amdgcn_s_barrier();
      __builtin_amdgcn_sched_barrier(0);
    }
  }

  float bv[4];
  #pragma unroll
  for (int nt=0;nt<4;++nt) bv[nt] = bias[nt*16 + l15];
  const int gy = y0 + wv;
  u16* outR = out + (size_t)n*HH*WW*64 + (size_t)gy*WW*64;
  #pragma unroll
  for (int mt=0; mt<4; ++mt){
    #pragma unroll
    for (int r=0; r<4; ++r){
      int x = x0 + mt*16 + lh*4 + r;
      u16* op = outR + (size_t)x*64 + l15;
      #pragma unroll
      for (int nt=0; nt<4; ++nt){
        float v = acc[mt][nt][r] + bv[nt];
        if (TANH) v = ftanh(v);
        op[nt*16] = f2bf(v);
      }
    }
  }
}

// Correlation via banded MFMA GEMM, operands straight from global.
// phi layout: [4 images][H][W][64]; images 0,1 = left, 2,3 = right.
__global__ __launch_bounds__(256) void corr_kernel(const u16* __restrict__ phi,
    float* __restrict__ out){
  __shared__ __align__(16) float band[128*65];     // 33280 B
  const int tid = threadIdx.x;
  int id = blockIdx.x;
  id = (id & 7)*1920 + (id >> 3);    // bijective: 15360 = 8*1920
  const int x0 = (id % 20)*64;
  const int y  = (id / 20) % 384;
  const int b  = id / 7680;
  const u16* Lrow = phi + ((size_t)((b    )*HH + y)*WW)*64;
  const u16* Rrow = phi + ((size_t)((b + 2)*HH + y)*WW)*64;

  const int lane = tid & 63;
  const int wv   = tid >> 6;        // wave owns G cols [wv*48, wv*48+48)
  const int l15  = lane & 15;
  const int lh   = lane >> 4;

  f32x4 acc[4][3];
  #pragma unroll
  for (int mt=0;mt<4;++mt)
    #pragma unroll
    for (int nt=0;nt<3;++nt) acc[mt][nt] = (f32x4){0.f,0.f,0.f,0.f};

  #pragma unroll
  for (int kh=0; kh<2; ++kh){
    const int koff = kh*32 + lh*8;  // u16 units within a pixel's 64 channels
    short8 a[4], bb[3];
    #pragma unroll
    for (int mt=0; mt<4; ++mt)
      a[mt] = *(const short8*)(Lrow + (size_t)(x0 + mt*16 + l15)*64 + koff);
    #pragma unroll
    for (int nt=0; nt<3; ++nt){
      int gx = x0 - 128 + wv*48 + nt*16 + l15;
      short8 z = (short8){0,0,0,0,0,0,0,0};
      bb[nt] = (gx >= 0) ? *(const short8*)(Rrow + (size_t)gx*64 + koff) : z;
    }
    #pragma unroll
    for (int mt=0; mt<4; ++mt)
      #pragma unroll
      for (int nt=0; nt<3; ++nt)
        acc[mt][nt] = __builtin_amdgcn_mfma_f32_16x16x32_bf16(a[mt], bb[nt], acc[mt][nt], 0,0,0);
  }

  // scatter diagonal band: x = D-row, jr = D-col, d = x - jr + 128
  #pragma unroll
  for (int mt=0; mt<4; ++mt){
    #pragma unroll
    for (int nt=0; nt<3; ++nt){
      int jr = wv*48 + nt*16 + l15;
      #pragma unroll
      for (int r=0; r<4; ++r){
        int x = mt*16 + lh*4 + r;
        int d = x - jr + 128;
        if ((unsigned)d < 128u) band[d*65 + x] = acc[mt][nt][r];
      }
    }
  }
  __syncthreads();

  // write out: 2048 float4 chunks (128 d-rows x 16), 256B contiguous per d-row
  float* ob = out + ((size_t)(b*128)*HH + (size_t)y)*WW + x0;
  #pragma unroll
  for (int it=0; it<8; ++it){
    int c = it*256 + tid;
    int d = c>>4, xq = c&15;
    const float* bp = &band[d*65 + xq*4];
    float4 v = make_float4(bp[0], bp[1], bp[2], bp[3]);
    *(float4*)&ob[(size_t)d*HH*WW + xq*4] = v;
  }
}

extern "C" void kernel_launch(void* const* d_in, const int* in_sizes, int n_in,
                              void* d_out, int out_size, void* d_ws, size_t ws_size,
                              hipStream_t stream){
  const float* l  = (const float*)d_in[0];
  const float* r  = (const float*)d_in[1];
  const float* W0 = (const float*)d_in[2];
  const float* b0 = (const float*)d_in[3];
  const float* W1 = (const float*)d_in[4];
  const float* b1 = (const float*)d_in[5];
  const float* W2 = (const float*)d_in[6];
  const float* b2 = (const float*)d_in[7];
  const float* W3 = (const float*)d_in[8];
  const float* b3 = (const float*)d_in[9];
  float* out = (float*)d_out;

  u16* wf   = (u16*)d_ws;                            // 110592 u16
  u16* wq0  = (u16*)((char*)d_ws + (512u<<10));      // 2048 u16 (conv0 B)
  u16* zpad = (u16*)((char*)d_ws + (1u<<20));        // 256 B zeros
  u16* B    = (u16*)((char*)d_ws + (2u<<20));        // pong: [4][H][W][64] bf16
  u16* A    = (u16*)d_out;                           // ping scratch inside d_out

  hipMemsetAsync(zpad, 0, 256, stream);
  prep_weights<<<dim3(440), dim3(256), 0, stream>>>(W1, W2, W3, W0, wf, wq0);

  conv0_kernel<<<dim3(20, 96, 4), dim3(256), 0, stream>>>(l, r, wq0, b0, A);
  conv64_kernel<true ><<<dim3(7680), dim3(256), 0, stream>>>(A, wf + 0*36864, b1, zpad, B);
  conv64_kernel<true ><<<dim3(7680), dim3(256), 0, stream>>>(B, wf + 1*36864, b2, zpad, A);
  conv64_kernel<false><<<dim3(7680), dim3(256), 0, stream>>>(A, wf + 2*36864, b3, zpad, B);

  corr_kernel<<<dim3(15360), dim3(256), 0, stream>>>(B, out);
}

// Round 20
// 843.885 us; speedup vs baseline: 1.0451x; 1.0071x over previous
//
#include <hip/hip_runtime.h>
#include <hip/hip_bf16.h>

#define HH 384
#define WW 1280

typedef unsigned short u16;
typedef unsigned int u32;
typedef __attribute__((ext_vector_type(8))) short short8;
typedef __attribute__((ext_vector_type(8))) unsigned short u16x8;
typedef __attribute__((ext_vector_type(4))) float f32x4;

__device__ __forceinline__ float bf2f(u16 u){ union{u32 i;float f;}v; v.i=((u32)u)<<16; return v.f; }
__device__ __forceinline__ u16 f2bf(float f){ union{float f;u32 i;}v; v.f=f; u32 r=v.i+0x7fffu+((v.i>>16)&1u); return (u16)(r>>16); }
// packed RNE f32x2 -> bf16x2 (v_cvt_pk_bf16_f32); low 16 bits = first value
__device__ __forceinline__ u32 f2bf_pk(float lo, float hi){
  __hip_bfloat162 h = __float22bfloat162_rn(make_float2(lo, hi));
  union{ __hip_bfloat162 h2; u32 w; } u; u.h2 = h; return u.w;
}
__device__ __forceinline__ float ftanh(float x){
  float e = __expf(2.0f*x);
  float r = __frcp_rn(e + 1.0f);
  return fmaf(-2.0f, r, 1.0f);
}
__device__ __forceinline__ void gload_lds16(const void* g, void* l){
  __builtin_amdgcn_global_load_lds((const __attribute__((address_space(1))) void*)g,
                                   (__attribute__((address_space(3))) void*)l, 16, 0, 0);
}

// Repack W1..W3 (OIHW f32) -> wf[layer][tap][oc][ic'] bf16 (conv64 swizzle
// pre-inverted: ic' = ic ^ ((oc&7)<<3)); W0 -> wq0[oc][k] bf16 with
// k = ic*9 + dy*3 + dx (k<27; 27..31 zero); also zero-fills zpad (256 B).
__global__ __launch_bounds__(256) void prep_weights(const float* __restrict__ W1,
    const float* __restrict__ W2, const float* __restrict__ W3,
    const float* __restrict__ W0, u16* __restrict__ wf, u16* __restrict__ wq0,
    u16* __restrict__ zpad){
  int idx = blockIdx.x*256 + threadIdx.x;          // 110592 + 2048 + 128
  if (idx < 110592){
    int m    = idx & 63;
    int oc   = (idx>>6) & 63;
    int tap  = (idx>>12) % 9;
    int layer= idx / 36864;
    int ic   = m ^ ((oc&7)<<3);
    const float* Ws = layer==0 ? W1 : (layer==1 ? W2 : W3);
    wf[idx] = f2bf(Ws[(oc*64+ic)*9 + tap]);
  } else if (idx < 110592 + 2048){
    int j  = idx - 110592;       // j = oc*32 + k
    int k  = j & 31;
    int oc = j >> 5;
    u16 v = 0;
    if (k < 27){
      int ic = k/9, rem = k - ic*9, dy = rem/3, dx = rem - dy*3;
      v = f2bf(W0[(oc*3+ic)*9 + dy*3 + dx]);
    }
    wq0[j] = v;
  } else if (idx < 110592 + 2048 + 128){
    zpad[idx - 110592 - 2048] = 0;
  }
}

// Layer 0 via im2col MFMA, LDS-staged gather. Block: 64x * 4y, 64 oc.
// Phase 1: stage f32 halo FB[3 ic][6 rows][72 cols] (col c <-> gx = x0-4+c,
// rows y0-1..y0+4) with aligned float4 loads; OOB -> 0. 80-float zero slot
// at FB[1296..] serves the k>=27 K-padding lanes.
// Phase 2: one 16x16x32 MFMA per (16px x 16oc) tile (K=27->32).
__global__ __launch_bounds__(256) void conv0_kernel(const float* __restrict__ l,
    const float* __restrict__ r, const u16* __restrict__ wq0,
    const float* __restrict__ b0, u16* __restrict__ out){
  __shared__ __align__(16) float FB[1376];
  const int tid = threadIdx.x;
  const int x0 = blockIdx.x*64;
  const int y0 = blockIdx.y*4;
  const int n  = blockIdx.z;
  const float* img = (n < 2 ? l : r) + (size_t)(n & 1)*3*HH*WW;

  // Phase 1: 344 float4 chunks (324 halo + 20 zero-slot)
  #pragma unroll
  for (int it=0; it<2; ++it){
    int e = it*256 + tid;
    if (e < 344){
      float4 v = make_float4(0.f,0.f,0.f,0.f);
      if (e < 324){
        int ic  = e / 108;
        int rem = e - ic*108;
        int row = rem / 18;
        int c4  = rem - row*18;
        int gy  = y0 - 1 + row;
        int gx0 = x0 - 4 + c4*4;
        if ((unsigned)gy < (unsigned)HH){
          const float* rp = img + ((size_t)ic*HH + gy)*WW;
          if (gx0 >= 0 && gx0 + 3 < WW){
            v = *(const float4*)(rp + gx0);
          } else {
            if ((unsigned)(gx0+0) < (unsigned)WW) v.x = rp[gx0+0];
            if ((unsigned)(gx0+1) < (unsigned)WW) v.y = rp[gx0+1];
            if ((unsigned)(gx0+2) < (unsigned)WW) v.z = rp[gx0+2];
            if ((unsigned)(gx0+3) < (unsigned)WW) v.w = rp[gx0+3];
          }
        }
      }
      *(float4*)&FB[e*4] = v;
    }
  }
  __syncthreads();

  const int lane = tid & 63;
  const int wv  = tid >> 6;
  const int l15 = lane & 15;
  const int lh  = lane >> 4;
  const int y   = y0 + wv;

  // per-lane k decode + LDS base (k = lh*8+e); k>=27 -> zero slot
  int baseE[8];
  #pragma unroll
  for (int e=0; e<8; ++e){
    int k  = lh*8 + e;
    bool ok = (k < 27);
    int kk = ok ? k : 0;
    int ic = kk/9, rem = kk - ic*9, dy = rem/3, dx = rem - dy*3;
    baseE[e] = ok ? (ic*432 + (wv + dy)*72 + dx + 3) : 1296;
  }

  // B-fragments: oc = nt*16 + l15, k-chunk lh*8 (prepacked bf16)
  short8 b[4];
  #pragma unroll
  for (int nt=0; nt<4; ++nt)
    b[nt] = *(const short8*)(wq0 + (size_t)(nt*16 + l15)*32 + lh*8);

  // A-fragments: LDS gather + packed bf16 (cvt_pk)
  short8 a[4];
  #pragma unroll
  for (int mt=0; mt<4; ++mt){
    int off = mt*16 + l15;
    float v[8];
    #pragma unroll
    for (int e=0; e<8; ++e) v[e] = FB[baseE[e] + off];
    union{ short8 s; u32 w[4]; } af;
    #pragma unroll
    for (int e=0; e<4; ++e) af.w[e] = f2bf_pk(v[2*e], v[2*e+1]);
    a[mt] = af.s;
  }

  f32x4 acc[4][4];
  #pragma unroll
  for (int mt=0;mt<4;++mt)
    #pragma unroll
    for (int nt=0;nt<4;++nt) acc[mt][nt] = (f32x4){0.f,0.f,0.f,0.f};
  #pragma unroll
  for (int mt=0; mt<4; ++mt)
    #pragma unroll
    for (int nt=0; nt<4; ++nt)
      acc[mt][nt] = __builtin_amdgcn_mfma_f32_16x16x32_bf16(a[mt], b[nt], acc[mt][nt], 0,0,0);

  float bv[4];
  #pragma unroll
  for (int nt=0;nt<4;++nt) bv[nt] = b0[nt*16 + l15];
  u16* outR = out + (size_t)n*HH*WW*64 + (size_t)y*WW*64;
  #pragma unroll
  for (int mt=0; mt<4; ++mt){
    #pragma unroll
    for (int nt=0; nt<4; ++nt){
      float v[4];
      #pragma unroll
      for (int rr=0; rr<4; ++rr) v[rr] = ftanh(acc[mt][nt][rr] + bv[nt]);
      u32 p0 = f2bf_pk(v[0], v[1]);
      u32 p1 = f2bf_pk(v[2], v[3]);
      u16 h[4] = { (u16)p0, (u16)(p0>>16), (u16)p1, (u16)(p1>>16) };
      #pragma unroll
      for (int rr=0; rr<4; ++rr){
        int x = x0 + mt*16 + lh*4 + rr;
        outR[(size_t)x*64 + nt*16 + l15] = h[rr];
      }
    }
  }
}

// Layers 1-3: 64->64 conv as 9 shifted MFMA GEMMs. NHWC bf16 in/out.
// Merged L/R: 7680 blocks, 1-D grid with XCD-bijective swizzle (7680 = 8*960).
// Input LDS [6 rows][66 cols][64 ic] swizzled, staged linearly from
// pre-swizzled src. Weight LDS wbuf[3], staged 2 taps ahead, counted-vmcnt
// raw barriers (no vmcnt(0) drain in the tap loop).
template<bool TANH>
__global__ __launch_bounds__(256) void conv64_kernel(const u16* __restrict__ in,
    const u16* __restrict__ wfL, const float* __restrict__ bias,
    const u16* __restrict__ zpad, u16* __restrict__ out){
  __shared__ __align__(16) u16 tile[6*66*64];      // 50688 B
  __shared__ __align__(16) u16 wbuf[3][4096];      // 3 x 8192 B
  const int tid = threadIdx.x;
  int id = blockIdx.x;
  id = (id & 7)*960 + (id >> 3);     // bijective: 7680 = 8*960
  const int x0 = (id % 20)*64;
  const int y0 = ((id / 20) % 96)*4;
  const int n  = id / 1920;          // [0,4): image index
  const u16* inN = in + (size_t)n*HH*WW*64;

  // stage input tile: 3168 16B-chunks, chunk q = (row*66+col)*8 + j
  for (int q0 = 0; q0 < 3168; q0 += 256){
    int q = q0 + tid;
    if (q < 3168){
      int row = q / 528;
      int rem = q - row*528;
      int col = rem >> 3;
      int j   = rem & 7;
      int gy = y0 - 1 + row;
      int gx = x0 - 1 + col;
      const u16* g;
      if ((unsigned)gy < (unsigned)HH && (unsigned)gx < (unsigned)WW)
        g = inN + (((size_t)(gy*WW + gx))<<6) + ((j ^ (col&7))<<3);
      else
        g = zpad + (j<<3);
      gload_lds16(g, &tile[(size_t)(q & ~63)*8]);
    }
  }
  // stage weights taps 0,1 -> wbuf[0], wbuf[1]
  #pragma unroll
  for (int t=0; t<2; ++t)
    #pragma unroll
    for (int c=0; c<2; ++c){
      int q = c*256 + tid;
      gload_lds16(wfL + (size_t)t*4096 + (size_t)q*8, &wbuf[t][(q & ~63)*8]);
    }
  asm volatile("s_waitcnt vmcnt(2)" ::: "memory");
  __builtin_amdgcn_s_barrier();
  __builtin_amdgcn_sched_barrier(0);

  const int lane = tid & 63;
  const int wv = tid >> 6;
  const int l15 = lane & 15;
  const int lh  = lane >> 4;

  f32x4 acc[4][4];
  #pragma unroll
  for (int mt=0;mt<4;++mt)
    #pragma unroll
    for (int nt=0;nt<4;++nt) acc[mt][nt] = (f32x4){0.f,0.f,0.f,0.f};

  #pragma unroll
  for (int tap = 0; tap < 9; ++tap){
    const int dy = tap/3, dx = tap%3;
    if (tap <= 6){               // prefetch tap+2 weights (2-deep pipeline)
      const u16* wsrc = wfL + (size_t)(tap+2)*4096;
      u16* wdst = wbuf[(tap+2)%3];
      #pragma unroll
      for (int c=0;c<2;++c){
        int q = c*256 + tid;
        gload_lds16(wsrc + (size_t)q*8, &wdst[(q & ~63)*8]);
      }
    }
    const char* wb = (const char*)wbuf[tap%3];
    const char* tb = (const char*)tile;
    const int xorA = ((l15 + dx)&7)<<4;
    const int xorB = (l15&7)<<4;
    #pragma unroll
    for (int kh=0; kh<2; ++kh){
      const int kbyte = kh*64 + lh*16;
      short8 a[4], b[4];
      #pragma unroll
      for (int mt=0; mt<4; ++mt){
        int col = mt*16 + l15 + dx;
        a[mt] = *(const short8*)(tb + ((wv+dy)*66 + col)*128 + (kbyte ^ xorA));
      }
      #pragma unroll
      for (int nt=0; nt<4; ++nt){
        int oc = nt*16 + l15;
        b[nt] = *(const short8*)(wb + oc*128 + (kbyte ^ xorB));
      }
      #pragma unroll
      for (int mt=0; mt<4; ++mt)
        #pragma unroll
        for (int nt=0; nt<4; ++nt)
          acc[mt][nt] = __builtin_amdgcn_mfma_f32_16x16x32_bf16(a[mt], b[nt], acc[mt][nt], 0,0,0);
    }
    if (tap < 8){
      if (tap <= 6) asm volatile("s_waitcnt vmcnt(2)" ::: "memory");
      else          asm volatile("s_waitcnt vmcnt(0)" ::: "memory");
      __builtin_amdgcn_s_barrier();
      __builtin_amdgcn_sched_barrier(0);
    }
  }

  float bv[4];
  #pragma unroll
  for (int nt=0;nt<4;++nt) bv[nt] = bias[nt*16 + l15];
  const int gy = y0 + wv;
  u16* outR = out + (size_t)n*HH*WW*64 + (size_t)gy*WW*64;
  #pragma unroll
  for (int mt=0; mt<4; ++mt){
    #pragma unroll
    for (int nt=0; nt<4; ++nt){
      float v[4];
      #pragma unroll
      for (int rr=0; rr<4; ++rr){
        v[rr] = acc[mt][nt][rr] + bv[nt];
        if (TANH) v[rr] = ftanh(v[rr]);
      }
      u32 p0 = f2bf_pk(v[0], v[1]);
      u32 p1 = f2bf_pk(v[2], v[3]);
      u16 h[4] = { (u16)p0, (u16)(p0>>16), (u16)p1, (u16)(p1>>16) };
      #pragma unroll
      for (int rr=0; rr<4; ++rr){
        int x = x0 + mt*16 + lh*4 + rr;
        outR[(size_t)x*64 + nt*16 + l15] = h[rr];
      }
    }
  }
}

// Correlation via banded MFMA GEMM, operands straight from global.
// phi layout: [4 images][H][W][64]; images 0,1 = left, 2,3 = right.
__global__ __launch_bounds__(256) void corr_kernel(const u16* __restrict__ phi,
    float* __restrict__ out){
  __shared__ __align__(16) float band[128*65];     // 33280 B
  const int tid = threadIdx.x;
  int id = blockIdx.x;
  id = (id & 7)*1920 + (id >> 3);    // bijective: 15360 = 8*1920
  const int x0 = (id % 20)*64;
  const int y  = (id / 20) % 384;
  const int b  = id / 7680;
  const u16* Lrow = phi + ((size_t)((b    )*HH + y)*WW)*64;
  const u16* Rrow = phi + ((size_t)((b + 2)*HH + y)*WW)*64;

  const int lane = tid & 63;
  const int wv   = tid >> 6;        // wave owns G cols [wv*48, wv*48+48)
  const int l15  = lane & 15;
  const int lh   = lane >> 4;

  f32x4 acc[4][3];
  #pragma unroll
  for (int mt=0;mt<4;++mt)
    #pragma unroll
    for (int nt=0;nt<3;++nt) acc[mt][nt] = (f32x4){0.f,0.f,0.f,0.f};

  #pragma unroll
  for (int kh=0; kh<2; ++kh){
    const int koff = kh*32 + lh*8;  // u16 units within a pixel's 64 channels
    short8 a[4], bb[3];
    #pragma unroll
    for (int mt=0; mt<4; ++mt)
      a[mt] = *(const short8*)(Lrow + (size_t)(x0 + mt*16 + l15)*64 + koff);
    #pragma unroll
    for (int nt=0; nt<3; ++nt){
      int gx = x0 - 128 + wv*48 + nt*16 + l15;
      short8 z = (short8){0,0,0,0,0,0,0,0};
      bb[nt] = (gx >= 0) ? *(const short8*)(Rrow + (size_t)gx*64 + koff) : z;
    }
    #pragma unroll
    for (int mt=0; mt<4; ++mt)
      #pragma unroll
      for (int nt=0; nt<3; ++nt)
        acc[mt][nt] = __builtin_amdgcn_mfma_f32_16x16x32_bf16(a[mt], bb[nt], acc[mt][nt], 0,0,0);
  }

  // scatter diagonal band: x = D-row, jr = D-col, d = x - jr + 128
  #pragma unroll
  for (int mt=0; mt<4; ++mt){
    #pragma unroll
    for (int nt=0; nt<3; ++nt){
      int jr = wv*48 + nt*16 + l15;
      #pragma unroll
      for (int r=0; r<4; ++r){
        int x = mt*16 + lh*4 + r;
        int d = x - jr + 128;
        if ((unsigned)d < 128u) band[d*65 + x] = acc[mt][nt][r];
      }
    }
  }
  __syncthreads();

  // write out: 2048 float4 chunks (128 d-rows x 16), 256B contiguous per d-row
  float* ob = out + ((size_t)(b*128)*HH + (size_t)y)*WW + x0;
  #pragma unroll
  for (int it=0; it<8; ++it){
    int c = it*256 + tid;
    int d = c>>4, xq = c&15;
    const float* bp = &band[d*65 + xq*4];
    float4 v = make_float4(bp[0], bp[1], bp[2], bp[3]);
    *(float4*)&ob[(size_t)d*HH*WW + xq*4] = v;
  }
}

extern "C" void kernel_launch(void* const* d_in, const int* in_sizes, int n_in,
                              void* d_out, int out_size, void* d_ws, size_t ws_size,
                              hipStream_t stream){
  const float* l  = (const float*)d_in[0];
  const float* r  = (const float*)d_in[1];
  const float* W0 = (const float*)d_in[2];
  const float* b0 = (const float*)d_in[3];
  const float* W1 = (const float*)d_in[4];
  const float* b1 = (const float*)d_in[5];
  const float* W2 = (const float*)d_in[6];
  const float* b2 = (const float*)d_in[7];
  const float* W3 = (const float*)d_in[8];
  const float* b3 = (const float*)d_in[9];
  float* out = (float*)d_out;

  u16* wf   = (u16*)d_ws;                            // 110592 u16
  u16* wq0  = (u16*)((char*)d_ws + (512u<<10));      // 2048 u16 (conv0 B)
  u16* zpad = (u16*)((char*)d_ws + (1u<<20));        // 256 B zeros (prep-filled)
  u16* B    = (u16*)((char*)d_ws + (2u<<20));        // pong: [4][H][W][64] bf16
  u16* A    = (u16*)d_out;                           // ping scratch inside d_out

  prep_weights<<<dim3(441), dim3(256), 0, stream>>>(W1, W2, W3, W0, wf, wq0, zpad);

  conv0_kernel<<<dim3(20, 96, 4), dim3(256), 0, stream>>>(l, r, wq0, b0, A);
  conv64_kernel<true ><<<dim3(7680), dim3(256), 0, stream>>>(A, wf + 0*36864, b1, zpad, B);
  conv64_kernel<true ><<<dim3(7680), dim3(256), 0, stream>>>(B, wf + 1*36864, b2, zpad, A);
  conv64_kernel<false><<<dim3(7680), dim3(256), 0, stream>>>(A, wf + 2*36864, b3, zpad, B);

  corr_kernel<<<dim3(15360), dim3(256), 0, stream>>>(B, out);
}